// Round 17
// baseline (108.986 us; speedup 1.0000x reference)
//
#include <hip/hip_runtime.h>
#include <hip/hip_bf16.h>
#include <stdint.h>

// B=8192 triplet loss with hard-negative mining.
// prep: normalize -> int8 (x127); loss recomputed exactly from fp32 x.
// dist_topk: R15 structure (counted-vmcnt dbuf i8 GEMM, 128x256 tile, BK=64,
//            4 K-steps, paired-row swizzle, fine interleave, setprio).
//            Mining: EXACT int keys (acc<<13)+(8191-ci) [2 ops] + inline-asm
//            v_med3_i32 insert [5 ops] -> 7 VALU/key (was 9).
// merge_loss: merge 32 sorted runs, threefry RNG, exact fp32 loss; fused
//            finalize via deterministic fixed-point u64 atomics + last-block.

#define NB 8192
#define NCG 32        // col-groups of 256
#define EPSF 1e-6f
#define IMIN (-2147483647 - 1)

typedef int i32x4 __attribute__((ext_vector_type(4)));

struct U2 { uint32_t x, y; };

__host__ __device__ __forceinline__ uint32_t rotl32(uint32_t v, int n) {
  return (v << n) | (v >> (32 - n));
}

__host__ __device__ __forceinline__ U2 tf2x32(uint32_t k0, uint32_t k1,
                                              uint32_t x0, uint32_t x1) {
  uint32_t k2 = k0 ^ k1 ^ 0x1BD11BDAu;
#define TF_R(r) { x0 += x1; x1 = rotl32(x1, r); x1 ^= x0; }
  x0 += k0; x1 += k1;
  TF_R(13) TF_R(15) TF_R(26) TF_R(6)
  x0 += k1; x1 += k2 + 1u;
  TF_R(17) TF_R(29) TF_R(16) TF_R(24)
  x0 += k2; x1 += k0 + 2u;
  TF_R(13) TF_R(15) TF_R(26) TF_R(6)
  x0 += k0; x1 += k1 + 3u;
  TF_R(17) TF_R(29) TF_R(16) TF_R(24)
  x0 += k1; x1 += k2 + 4u;
  TF_R(13) TF_R(15) TF_R(26) TF_R(6)
  x0 += k2; x1 += k0 + 5u;
#undef TF_R
  U2 r; r.x = x0; r.y = x1; return r;
}

__device__ __forceinline__ uint32_t rng_word(U2 r) { return r.x ^ r.y; }

// int top-5 insert into sorted-desc T0..T4. Valid because T0>=T1>=..>=T4:
// new Ti = med3(c, T(i-1), Ti). 1 max + 4 v_med3_i32.
#define FINS5I(T0, T1, T2, T3, T4, C) {           \
    const int _c = (C), _t0 = T0, _t1 = T1, _t2 = T2, _t3 = T3, _t4 = T4; \
    T0 = _t0 > _c ? _t0 : _c;                     \
    asm("v_med3_i32 %0, %1, %2, %3" : "=v"(T1) : "v"(_c), "v"(_t0), "v"(_t1)); \
    asm("v_med3_i32 %0, %1, %2, %3" : "=v"(T2) : "v"(_c), "v"(_t1), "v"(_t2)); \
    asm("v_med3_i32 %0, %1, %2, %3" : "=v"(T3) : "v"(_c), "v"(_t2), "v"(_t3)); \
    asm("v_med3_i32 %0, %1, %2, %3" : "=v"(T4) : "v"(_c), "v"(_t3), "v"(_t4)); }

__device__ __forceinline__ void gload16(const void* g, void* l) {
  __builtin_amdgcn_global_load_lds(
      (const __attribute__((address_space(1))) unsigned int*)g,
      (__attribute__((address_space(3))) unsigned int*)l, 16, 0, 0);
}

// ---------------- prep: normalize -> int8 (x127) ----------------
__global__ __launch_bounds__(256) void prep_kernel(
    const float* __restrict__ x,
    char* __restrict__ aq8, char* __restrict__ pq8) {
  const int w = threadIdx.x >> 6, l = threadIdx.x & 63;
  const int row = blockIdx.x * 4 + w;
  const float4* xr = (const float4*)(x + (size_t)row * 512);
  const float4 a4 = xr[l];
  const float4 p4 = xr[64 + l];
  float sa = a4.x * a4.x + a4.y * a4.y + a4.z * a4.z + a4.w * a4.w;
  float sp = p4.x * p4.x + p4.y * p4.y + p4.z * p4.z + p4.w * p4.w;
#pragma unroll
  for (int off = 32; off; off >>= 1) { sa += __shfl_xor(sa, off); sp += __shfl_xor(sp, off); }
  const float ia = 127.0f / fmaxf(sqrtf(sa), 1e-12f);
  const float ip_ = 127.0f / fmaxf(sqrtf(sp), 1e-12f);
  const int qa0 = (int)rintf(a4.x * ia), qa1 = (int)rintf(a4.y * ia);
  const int qa2 = (int)rintf(a4.z * ia), qa3 = (int)rintf(a4.w * ia);
  const int qp0 = (int)rintf(p4.x * ip_), qp1 = (int)rintf(p4.y * ip_);
  const int qp2 = (int)rintf(p4.z * ip_), qp3 = (int)rintf(p4.w * ip_);
  const uint32_t ua = (qa0 & 255) | ((qa1 & 255) << 8) |
                      ((qa2 & 255) << 16) | ((uint32_t)(qa3 & 255) << 24);
  const uint32_t up = (qp0 & 255) | ((qp1 & 255) << 8) |
                      ((qp2 & 255) << 16) | ((uint32_t)(qp3 & 255) << 24);
  *(uint32_t*)(aq8 + (size_t)row * 256 + l * 4) = ua;
  *(uint32_t*)(pq8 + (size_t)row * 256 + l * 4) = up;
}

// ---------------- dist + per-row top-5 (i8) ----------------
// grid: 2048 blocks (64 rb x 32 cb, XCD supertile), 512 thr = 8 waves (2x4);
// wave (wr,wc) owns a-rows [rb*128+wr*64,+64) x p-cols [cb*256+wc*64,+64).
// LDS: 2 K-buffers x 24KB (A 128x64B 8KB + B 256x64B 16KB). Paired-row
// swizzle (0 conflicts): logical row r (64B), slot t -> macro-row R=r>>1,
// slot ((r&1)*4+t)^(R&7). 4 K-steps of BK=64 (mfma_i32_16x16x64_i8).
// mfma(bF, aF): a-row (C col) = row0+wr*64+aq*16+lo;
// p-col (C row) = col0+wc*64+pq*16+hi*4+r.
__global__ __launch_bounds__(512, 2) void dist_topk_kernel(
    const char* __restrict__ aq8, const char* __restrict__ pq8,
    int* __restrict__ part) {
  __shared__ __align__(16) char smem[49152]; // buf0|buf1; reused as mls[128][81]

  const int tid = threadIdx.x;
  const int w = tid >> 6, l = tid & 63;
  const int lo = l & 15, hi = l >> 4;
  const int wr = w >> 2, wc = w & 3;

  const int b = blockIdx.x;
  const int xcd = b & 7, j = b >> 3;          // j: 0..255
  const int rb = (xcd >> 1) * 16 + (j >> 4);  // 0..63 (128 rows)
  const int cb = (xcd & 1) * 16 + (j & 15);   // 0..31 (256 cols)
  const int row0 = rb * 128, col0 = cb * 256;
  const bool hasDiag = (cb == (rb >> 1));

  i32x4 acc[4][4];
#pragma unroll
  for (int aq = 0; aq < 4; ++aq)
#pragma unroll
    for (int pq = 0; pq < 4; ++pq) { i32x4 z = {0, 0, 0, 0}; acc[aq][pq] = z; }

#define STAGE(BUF, KS)                                                        \
  {                                                                           \
    { const int off = tid * 16;                                               \
      const int R = off >> 7;                                                 \
      const int s = ((off >> 4) & 7) ^ (R & 7);                               \
      const int r = 2 * R + (s >> 2);                                         \
      const int kb = (s & 3) * 16;                                            \
      gload16(aq8 + (size_t)(row0 + r) * 256 + (KS) * 64 + kb,                \
              smem + (BUF) * 24576 + off); }                                  \
    _Pragma("unroll")                                                         \
    for (int jj = 0; jj < 2; ++jj) {                                          \
      const int off = jj * 8192 + tid * 16;                                   \
      const int R = off >> 7;                                                 \
      const int s = ((off >> 4) & 7) ^ (R & 7);                               \
      const int c = 2 * R + (s >> 2);                                         \
      const int kb = (s & 3) * 16;                                            \
      gload16(pq8 + (size_t)(col0 + c) * 256 + (KS) * 64 + kb,                \
              smem + (BUF) * 24576 + 8192 + off); }                           \
  }

#define LADDR(RR, T) (((RR) >> 1) * 128 + (((((RR) & 1) * 4 + (T)) ^ (((RR) >> 1) & 7)) * 16))

#define COMPUTE(BUF)                                                          \
  {                                                                           \
    i32x4 aF0, aF1, aF2, aF3, bF0, bF1, bF2, bF3;                             \
    { const int r = wr * 64 + 0 + lo;                                         \
      aF0 = __builtin_bit_cast(i32x4, *(const uint4*)(smem + (BUF) * 24576 + LADDR(r, hi))); } \
    { const int r = wr * 64 + 16 + lo;                                        \
      aF1 = __builtin_bit_cast(i32x4, *(const uint4*)(smem + (BUF) * 24576 + LADDR(r, hi))); } \
    { const int r = wr * 64 + 32 + lo;                                        \
      aF2 = __builtin_bit_cast(i32x4, *(const uint4*)(smem + (BUF) * 24576 + LADDR(r, hi))); } \
    { const int r = wr * 64 + 48 + lo;                                        \
      aF3 = __builtin_bit_cast(i32x4, *(const uint4*)(smem + (BUF) * 24576 + LADDR(r, hi))); } \
    { const int c = wc * 64 + 0 + lo;                                         \
      bF0 = __builtin_bit_cast(i32x4, *(const uint4*)(smem + (BUF) * 24576 + 8192 + LADDR(c, hi))); } \
    { const int c = wc * 64 + 16 + lo;                                        \
      bF1 = __builtin_bit_cast(i32x4, *(const uint4*)(smem + (BUF) * 24576 + 8192 + LADDR(c, hi))); } \
    __builtin_amdgcn_s_setprio(1);                                            \
    acc[0][0] = __builtin_amdgcn_mfma_i32_16x16x64_i8(bF0, aF0, acc[0][0], 0, 0, 0); \
    acc[1][0] = __builtin_amdgcn_mfma_i32_16x16x64_i8(bF0, aF1, acc[1][0], 0, 0, 0); \
    acc[2][0] = __builtin_amdgcn_mfma_i32_16x16x64_i8(bF0, aF2, acc[2][0], 0, 0, 0); \
    acc[3][0] = __builtin_amdgcn_mfma_i32_16x16x64_i8(bF0, aF3, acc[3][0], 0, 0, 0); \
    { const int c = wc * 64 + 32 + lo;                                        \
      bF2 = __builtin_bit_cast(i32x4, *(const uint4*)(smem + (BUF) * 24576 + 8192 + LADDR(c, hi))); } \
    acc[0][1] = __builtin_amdgcn_mfma_i32_16x16x64_i8(bF1, aF0, acc[0][1], 0, 0, 0); \
    acc[1][1] = __builtin_amdgcn_mfma_i32_16x16x64_i8(bF1, aF1, acc[1][1], 0, 0, 0); \
    acc[2][1] = __builtin_amdgcn_mfma_i32_16x16x64_i8(bF1, aF2, acc[2][1], 0, 0, 0); \
    acc[3][1] = __builtin_amdgcn_mfma_i32_16x16x64_i8(bF1, aF3, acc[3][1], 0, 0, 0); \
    { const int c = wc * 64 + 48 + lo;                                        \
      bF3 = __builtin_bit_cast(i32x4, *(const uint4*)(smem + (BUF) * 24576 + 8192 + LADDR(c, hi))); } \
    acc[0][2] = __builtin_amdgcn_mfma_i32_16x16x64_i8(bF2, aF0, acc[0][2], 0, 0, 0); \
    acc[1][2] = __builtin_amdgcn_mfma_i32_16x16x64_i8(bF2, aF1, acc[1][2], 0, 0, 0); \
    acc[2][2] = __builtin_amdgcn_mfma_i32_16x16x64_i8(bF2, aF2, acc[2][2], 0, 0, 0); \
    acc[3][2] = __builtin_amdgcn_mfma_i32_16x16x64_i8(bF2, aF3, acc[3][2], 0, 0, 0); \
    acc[0][3] = __builtin_amdgcn_mfma_i32_16x16x64_i8(bF3, aF0, acc[0][3], 0, 0, 0); \
    acc[1][3] = __builtin_amdgcn_mfma_i32_16x16x64_i8(bF3, aF1, acc[1][3], 0, 0, 0); \
    acc[2][3] = __builtin_amdgcn_mfma_i32_16x16x64_i8(bF3, aF2, acc[2][3], 0, 0, 0); \
    acc[3][3] = __builtin_amdgcn_mfma_i32_16x16x64_i8(bF3, aF3, acc[3][3], 0, 0, 0); \
    __builtin_amdgcn_s_setprio(0);                                            \
  }

#define WAITV3 { asm volatile("s_waitcnt vmcnt(3)" ::: "memory"); }
#define WAITV0 { asm volatile("s_waitcnt vmcnt(0)" ::: "memory"); }
#define BAR    { __builtin_amdgcn_s_barrier(); }

  STAGE(0, 0)
  STAGE(1, 1) WAITV3 BAR COMPUTE(0) BAR   // s=0
  STAGE(0, 2) WAITV3 BAR COMPUTE(1) BAR   // s=1
  STAGE(1, 3) WAITV3 BAR COMPUTE(0) BAR   // s=2
  WAITV0 BAR COMPUTE(1)                   // s=3

#undef STAGE
#undef LADDR
#undef COMPUTE
#undef WAITV3
#undef WAITV0
#undef BAR

  // epilogue: exact int keys; mls in the (retired) K-buffers.
  __syncthreads();
  int* mls = (int*)smem;                      // [128 rows][81] int = 41.5KB
  const int vb13 = 8191 - (col0 + wc * 64) - hi * 4;
#pragma unroll
  for (int aq = 0; aq < 4; ++aq) {
    int T0 = IMIN, T1 = IMIN, T2 = IMIN, T3 = IMIN, T4 = IMIN;
    const int arow = row0 + wr * 64 + aq * 16 + lo;
#pragma unroll
    for (int pq = 0; pq < 4; ++pq)
#pragma unroll
      for (int rr = 0; rr < 4; ++rr) {
        int key = (int)(((uint32_t)acc[aq][pq][rr]) << 13) + vb13 - (pq * 16 + rr);
        if (hasDiag) {
          if (col0 + wc * 64 + pq * 16 + hi * 4 + rr == arow) key = IMIN;
        }
        FINS5I(T0, T1, T2, T3, T4, key);
      }
    int* dst = mls + (wr * 64 + aq * 16 + lo) * 81 + (wc * 4 + hi) * 5;
    dst[0] = T0; dst[1] = T1; dst[2] = T2; dst[3] = T3; dst[4] = T4;
  }
  __syncthreads();

  // block-level merge: 2 threads/row x 40 keys, then shfl_xor(1) pair-merge
  if (tid < 256) {
    const int row = tid >> 1, half = tid & 1;
    const int* s2 = mls + row * 81 + half * 40;
    int M0 = IMIN, M1 = IMIN, M2 = IMIN, M3 = IMIN, M4 = IMIN;
#pragma unroll
    for (int k = 0; k < 40; ++k) FINS5I(M0, M1, M2, M3, M4, s2[k]);
    const int c0 = __shfl_xor(M0, 1), c1 = __shfl_xor(M1, 1),
              c2 = __shfl_xor(M2, 1), c3 = __shfl_xor(M3, 1),
              c4 = __shfl_xor(M4, 1);
    FINS5I(M0, M1, M2, M3, M4, c0);
    FINS5I(M0, M1, M2, M3, M4, c1);
    FINS5I(M0, M1, M2, M3, M4, c2);
    FINS5I(M0, M1, M2, M3, M4, c3);
    FINS5I(M0, M1, M2, M3, M4, c4);
    if (half == 0) {
      int* dst = part + ((size_t)(row0 + row) * NCG + cb) * 5;
      dst[0] = M0; dst[1] = M1; dst[2] = M2; dst[3] = M3; dst[4] = M4;
    }
  }
}

// ------- merge splits + RNG + exact fp32 loss + fused deterministic mean -------
__global__ __launch_bounds__(256) void merge_loss_kernel(
    const float* __restrict__ x, const int* __restrict__ part,
    unsigned long long* __restrict__ acc64, unsigned int* __restrict__ cnt,
    float* __restrict__ out,
    uint32_t k1a, uint32_t k1b, uint32_t k2a, uint32_t k2b) {
  const int w = threadIdx.x >> 6, l = threadIdx.x & 63;
  const int i = blockIdx.x * 4 + w;
  __shared__ int cs[4][160];
  __shared__ unsigned long long bsum[4];
  const int* src = part + (size_t)i * (NCG * 5);
  cs[w][l] = src[l];
  cs[w][64 + l] = src[64 + l];
  if (l < 32) cs[w][128 + l] = src[128 + l];
  __syncthreads();

  int T0 = IMIN, T1 = IMIN, T2 = IMIN, T3 = IMIN, T4 = IMIN;
  for (int rch = 0; rch < NCG; ++rch) {
    for (int q = 0; q < 5; ++q) {      // runs sorted desc -> early out (uniform)
      const int c = cs[w][rch * 5 + q];
      if (c <= T4) break;
      FINS5I(T0, T1, T2, T3, T4, c);
    }
  }

  // RNG: coin = uniform(k1) < 0.5 <=> MSB==0 ; randint(k2,0,5)
  const uint32_t cw = rng_word(tf2x32(k1a, k1b, 0u, (uint32_t)i));
  const bool coin = (cw >> 31) == 0u;
  const uint32_t hb = rng_word(tf2x32(k2a, k2b, 0u, (uint32_t)i));
  const uint32_t lb = rng_word(tf2x32(k2a, k2b, 0u, (uint32_t)(NB + i)));
  const int rr = (int)(((hb % 5u) + (lb % 5u)) % 5u);
  const int rank = coin ? 0 : rr;
  const int kch = (rank == 0) ? T0 : (rank == 1) ? T1 : (rank == 2) ? T2
                : (rank == 3) ? T3 : T4;
  const int neg = 8191 - (kch & 8191);

  // exact fp32 loss from raw x
  const float4 xa = *(const float4*)(x + (size_t)i * 512 + l * 4);
  const float4 xp = *(const float4*)(x + (size_t)i * 512 + 256 + l * 4);
  const float4 xn = *(const float4*)(x + (size_t)neg * 512 + 256 + l * 4);
  float sa = xa.x * xa.x + xa.y * xa.y + xa.z * xa.z + xa.w * xa.w;
  float sp = xp.x * xp.x + xp.y * xp.y + xp.z * xp.z + xp.w * xp.w;
  float sn = xn.x * xn.x + xn.y * xn.y + xn.z * xn.z + xn.w * xn.w;
#pragma unroll
  for (int off = 32; off; off >>= 1) {
    sa += __shfl_xor(sa, off); sp += __shfl_xor(sp, off); sn += __shfl_xor(sn, off);
  }
  const float na = fmaxf(sqrtf(sa), 1e-12f);
  const float np = fmaxf(sqrtf(sp), 1e-12f);
  const float nn = fmaxf(sqrtf(sn), 1e-12f);

  float pos = 0.f, ng = 0.f;
  {
    float av, pv, nv, dp, dn;
    av = xa.x / na; pv = xp.x / np; nv = xn.x / nn;
    dp = av - pv + EPSF; pos += dp * dp; dn = av - nv + EPSF; ng += dn * dn;
    av = xa.y / na; pv = xp.y / np; nv = xn.y / nn;
    dp = av - pv + EPSF; pos += dp * dp; dn = av - nv + EPSF; ng += dn * dn;
    av = xa.z / na; pv = xp.z / np; nv = xn.z / nn;
    dp = av - pv + EPSF; pos += dp * dp; dn = av - nv + EPSF; ng += dn * dn;
    av = xa.w / na; pv = xp.w / np; nv = xn.w / nn;
    dp = av - pv + EPSF; pos += dp * dp; dn = av - nv + EPSF; ng += dn * dn;
  }
#pragma unroll
  for (int off = 32; off; off >>= 1) {
    pos += __shfl_xor(pos, off); ng += __shfl_xor(ng, off);
  }
  if (l == 0) {
    const float rl = fmaxf(pos - ng, 0.0f);
    bsum[w] = (unsigned long long)((double)rl * 4294967296.0); // 32.32 fixed pt
  }
  __syncthreads();

  if (threadIdx.x == 0) {
    const unsigned long long s4 = bsum[0] + bsum[1] + bsum[2] + bsum[3];
    atomicAdd(acc64, s4);
    __threadfence();
    const unsigned int old = atomicAdd(cnt, 1u);
    if (old == gridDim.x - 1) {
      const unsigned long long total = atomicAdd(acc64, 0ULL);
      out[0] = (float)((double)total / 4294967296.0 / (double)NB);
    }
  }
}

extern "C" void kernel_launch(void* const* d_in, const int* in_sizes, int n_in,
                              void* d_out, int out_size, void* d_ws, size_t ws_size,
                              hipStream_t stream) {
  (void)in_sizes; (void)n_in; (void)out_size; (void)ws_size;
  const float* x = (const float*)d_in[0];
  float* out = (float*)d_out;
  char* ws = (char*)d_ws;

  char* aq8 = ws;                                                        // 2 MB
  char* pq8 = ws + (size_t)2 * 1024 * 1024;                              // 2 MB
  int* part = (int*)(ws + (size_t)4 * 1024 * 1024);                      // 5.24 MB
  char* tail = ws + (size_t)4 * 1024 * 1024 +
               (size_t)NB * NCG * 5 * sizeof(int);
  unsigned long long* acc64 = (unsigned long long*)tail;                 // 8 B
  unsigned int* cnt = (unsigned int*)(tail + 8);                         // 4 B

  // JAX: kr = key(1); k1, k2 = split(kr)  (threefry partitionable)
  U2 c0 = tf2x32(0u, 1u, 0u, 0u);
  U2 c1 = tf2x32(0u, 1u, 0u, 1u);
  const uint32_t k1a = c0.x, k1b = c0.y;
  const uint32_t k2a = c1.x, k2b = c1.y;

  hipMemsetAsync(tail, 0, 16, stream);
  prep_kernel<<<NB / 4, 256, 0, stream>>>(x, aq8, pq8);
  dist_topk_kernel<<<2048, 512, 0, stream>>>(aq8, pq8, part);
  merge_loss_kernel<<<NB / 4, 256, 0, stream>>>(x, part, acc64, cnt, out,
                                                k1a, k1b, k2a, k2b);
}

// Round 18
// 60.194 us; speedup vs baseline: 1.8106x; 1.8106x over previous
//
#include <hip/hip_runtime.h>
#include <hip/hip_bf16.h>
#include <stdint.h>

// B=8192 triplet loss with hard-negative mining.
// prep: normalize -> int8 (x127); loss recomputed exactly from fp32 x.
// dist_topk: counted-vmcnt dbuf i8 GEMM (128x256 tile, BK=64, 4 K-steps,
//            paired-row swizzle, fine interleave, setprio). Mining: EXACT
//            int keys (acc<<13)+(8191-ci) + v_med3_i32 insert (absmax 0.0,
//            R17-proven). mls in retired K-buffers, 2-thread/row merge.
// merge_loss: merge 32 sorted runs -> rowloss (NO atomics/fences — R17's
//            fused finalize cost 66us in fence-storms).
// finalize: deterministic mean (1 block).

#define NB 8192
#define NCG 32        // col-groups of 256
#define EPSF 1e-6f
#define IMIN (-2147483647 - 1)

typedef int i32x4 __attribute__((ext_vector_type(4)));

struct U2 { uint32_t x, y; };

__host__ __device__ __forceinline__ uint32_t rotl32(uint32_t v, int n) {
  return (v << n) | (v >> (32 - n));
}

__host__ __device__ __forceinline__ U2 tf2x32(uint32_t k0, uint32_t k1,
                                              uint32_t x0, uint32_t x1) {
  uint32_t k2 = k0 ^ k1 ^ 0x1BD11BDAu;
#define TF_R(r) { x0 += x1; x1 = rotl32(x1, r); x1 ^= x0; }
  x0 += k0; x1 += k1;
  TF_R(13) TF_R(15) TF_R(26) TF_R(6)
  x0 += k1; x1 += k2 + 1u;
  TF_R(17) TF_R(29) TF_R(16) TF_R(24)
  x0 += k2; x1 += k0 + 2u;
  TF_R(13) TF_R(15) TF_R(26) TF_R(6)
  x0 += k0; x1 += k1 + 3u;
  TF_R(17) TF_R(29) TF_R(16) TF_R(24)
  x0 += k1; x1 += k2 + 4u;
  TF_R(13) TF_R(15) TF_R(26) TF_R(6)
  x0 += k2; x1 += k0 + 5u;
#undef TF_R
  U2 r; r.x = x0; r.y = x1; return r;
}

__device__ __forceinline__ uint32_t rng_word(U2 r) { return r.x ^ r.y; }

// int top-5 insert into sorted-desc T0..T4 via med3 (valid since T sorted):
// asm version for the hot mining loop.
#define FINS5I(T0, T1, T2, T3, T4, C) {           \
    const int _c = (C), _t0 = T0, _t1 = T1, _t2 = T2, _t3 = T3, _t4 = T4; \
    T0 = _t0 > _c ? _t0 : _c;                     \
    asm("v_med3_i32 %0, %1, %2, %3" : "=v"(T1) : "v"(_c), "v"(_t0), "v"(_t1)); \
    asm("v_med3_i32 %0, %1, %2, %3" : "=v"(T2) : "v"(_c), "v"(_t1), "v"(_t2)); \
    asm("v_med3_i32 %0, %1, %2, %3" : "=v"(T3) : "v"(_c), "v"(_t2), "v"(_t3)); \
    asm("v_med3_i32 %0, %1, %2, %3" : "=v"(T4) : "v"(_c), "v"(_t3), "v"(_t4)); }

// plain C version (merge_loss; compiler emits med3 itself, no asm in
// early-out control flow)
#define FINS5C(T0, T1, T2, T3, T4, C) {           \
    const int _t0 = T0, _t1 = T1, _t2 = T2, _t3 = T3, _t4 = T4, _c = C; \
    T0 = _t0 > _c ? _t0 : _c;                     \
    { const int m = _c < _t0 ? _c : _t0; T1 = _t1 > m ? _t1 : m; } \
    { const int m = _c < _t1 ? _c : _t1; T2 = _t2 > m ? _t2 : m; } \
    { const int m = _c < _t2 ? _c : _t2; T3 = _t3 > m ? _t3 : m; } \
    { const int m = _c < _t3 ? _c : _t3; T4 = _t4 > m ? _t4 : m; } }

__device__ __forceinline__ void gload16(const void* g, void* l) {
  __builtin_amdgcn_global_load_lds(
      (const __attribute__((address_space(1))) unsigned int*)g,
      (__attribute__((address_space(3))) unsigned int*)l, 16, 0, 0);
}

// ---------------- prep: normalize -> int8 (x127) ----------------
__global__ __launch_bounds__(256) void prep_kernel(
    const float* __restrict__ x,
    char* __restrict__ aq8, char* __restrict__ pq8) {
  const int w = threadIdx.x >> 6, l = threadIdx.x & 63;
  const int row = blockIdx.x * 4 + w;
  const float4* xr = (const float4*)(x + (size_t)row * 512);
  const float4 a4 = xr[l];
  const float4 p4 = xr[64 + l];
  float sa = a4.x * a4.x + a4.y * a4.y + a4.z * a4.z + a4.w * a4.w;
  float sp = p4.x * p4.x + p4.y * p4.y + p4.z * p4.z + p4.w * p4.w;
#pragma unroll
  for (int off = 32; off; off >>= 1) { sa += __shfl_xor(sa, off); sp += __shfl_xor(sp, off); }
  const float ia = 127.0f / fmaxf(sqrtf(sa), 1e-12f);
  const float ip_ = 127.0f / fmaxf(sqrtf(sp), 1e-12f);
  const int qa0 = (int)rintf(a4.x * ia), qa1 = (int)rintf(a4.y * ia);
  const int qa2 = (int)rintf(a4.z * ia), qa3 = (int)rintf(a4.w * ia);
  const int qp0 = (int)rintf(p4.x * ip_), qp1 = (int)rintf(p4.y * ip_);
  const int qp2 = (int)rintf(p4.z * ip_), qp3 = (int)rintf(p4.w * ip_);
  const uint32_t ua = (qa0 & 255) | ((qa1 & 255) << 8) |
                      ((qa2 & 255) << 16) | ((uint32_t)(qa3 & 255) << 24);
  const uint32_t up = (qp0 & 255) | ((qp1 & 255) << 8) |
                      ((qp2 & 255) << 16) | ((uint32_t)(qp3 & 255) << 24);
  *(uint32_t*)(aq8 + (size_t)row * 256 + l * 4) = ua;
  *(uint32_t*)(pq8 + (size_t)row * 256 + l * 4) = up;
}

// ---------------- dist + per-row top-5 (i8) ----------------
// grid: 2048 blocks (64 rb x 32 cb, XCD supertile), 512 thr = 8 waves (2x4);
// wave (wr,wc) owns a-rows [rb*128+wr*64,+64) x p-cols [cb*256+wc*64,+64).
// LDS: 2 K-buffers x 24KB (A 128x64B 8KB + B 256x64B 16KB). Paired-row
// swizzle (0 conflicts): logical row r (64B), slot t -> macro-row R=r>>1,
// slot ((r&1)*4+t)^(R&7). 4 K-steps of BK=64 (mfma_i32_16x16x64_i8).
// mfma(bF, aF): a-row (C col) = row0+wr*64+aq*16+lo;
// p-col (C row) = col0+wc*64+pq*16+hi*4+r.
__global__ __launch_bounds__(512, 2) void dist_topk_kernel(
    const char* __restrict__ aq8, const char* __restrict__ pq8,
    int* __restrict__ part) {
  __shared__ __align__(16) char smem[49152]; // buf0|buf1; reused as mls[128][81]

  const int tid = threadIdx.x;
  const int w = tid >> 6, l = tid & 63;
  const int lo = l & 15, hi = l >> 4;
  const int wr = w >> 2, wc = w & 3;

  const int b = blockIdx.x;
  const int xcd = b & 7, j = b >> 3;          // j: 0..255
  const int rb = (xcd >> 1) * 16 + (j >> 4);  // 0..63 (128 rows)
  const int cb = (xcd & 1) * 16 + (j & 15);   // 0..31 (256 cols)
  const int row0 = rb * 128, col0 = cb * 256;
  const bool hasDiag = (cb == (rb >> 1));

  i32x4 acc[4][4];
#pragma unroll
  for (int aq = 0; aq < 4; ++aq)
#pragma unroll
    for (int pq = 0; pq < 4; ++pq) { i32x4 z = {0, 0, 0, 0}; acc[aq][pq] = z; }

#define STAGE(BUF, KS)                                                        \
  {                                                                           \
    { const int off = tid * 16;                                               \
      const int R = off >> 7;                                                 \
      const int s = ((off >> 4) & 7) ^ (R & 7);                               \
      const int r = 2 * R + (s >> 2);                                         \
      const int kb = (s & 3) * 16;                                            \
      gload16(aq8 + (size_t)(row0 + r) * 256 + (KS) * 64 + kb,                \
              smem + (BUF) * 24576 + off); }                                  \
    _Pragma("unroll")                                                         \
    for (int jj = 0; jj < 2; ++jj) {                                          \
      const int off = jj * 8192 + tid * 16;                                   \
      const int R = off >> 7;                                                 \
      const int s = ((off >> 4) & 7) ^ (R & 7);                               \
      const int c = 2 * R + (s >> 2);                                         \
      const int kb = (s & 3) * 16;                                            \
      gload16(pq8 + (size_t)(col0 + c) * 256 + (KS) * 64 + kb,                \
              smem + (BUF) * 24576 + 8192 + off); }                           \
  }

#define LADDR(RR, T) (((RR) >> 1) * 128 + (((((RR) & 1) * 4 + (T)) ^ (((RR) >> 1) & 7)) * 16))

#define COMPUTE(BUF)                                                          \
  {                                                                           \
    i32x4 aF0, aF1, aF2, aF3, bF0, bF1, bF2, bF3;                             \
    { const int r = wr * 64 + 0 + lo;                                         \
      aF0 = __builtin_bit_cast(i32x4, *(const uint4*)(smem + (BUF) * 24576 + LADDR(r, hi))); } \
    { const int r = wr * 64 + 16 + lo;                                        \
      aF1 = __builtin_bit_cast(i32x4, *(const uint4*)(smem + (BUF) * 24576 + LADDR(r, hi))); } \
    { const int r = wr * 64 + 32 + lo;                                        \
      aF2 = __builtin_bit_cast(i32x4, *(const uint4*)(smem + (BUF) * 24576 + LADDR(r, hi))); } \
    { const int r = wr * 64 + 48 + lo;                                        \
      aF3 = __builtin_bit_cast(i32x4, *(const uint4*)(smem + (BUF) * 24576 + LADDR(r, hi))); } \
    { const int c = wc * 64 + 0 + lo;                                         \
      bF0 = __builtin_bit_cast(i32x4, *(const uint4*)(smem + (BUF) * 24576 + 8192 + LADDR(c, hi))); } \
    { const int c = wc * 64 + 16 + lo;                                        \
      bF1 = __builtin_bit_cast(i32x4, *(const uint4*)(smem + (BUF) * 24576 + 8192 + LADDR(c, hi))); } \
    __builtin_amdgcn_s_setprio(1);                                            \
    acc[0][0] = __builtin_amdgcn_mfma_i32_16x16x64_i8(bF0, aF0, acc[0][0], 0, 0, 0); \
    acc[1][0] = __builtin_amdgcn_mfma_i32_16x16x64_i8(bF0, aF1, acc[1][0], 0, 0, 0); \
    acc[2][0] = __builtin_amdgcn_mfma_i32_16x16x64_i8(bF0, aF2, acc[2][0], 0, 0, 0); \
    acc[3][0] = __builtin_amdgcn_mfma_i32_16x16x64_i8(bF0, aF3, acc[3][0], 0, 0, 0); \
    { const int c = wc * 64 + 32 + lo;                                        \
      bF2 = __builtin_bit_cast(i32x4, *(const uint4*)(smem + (BUF) * 24576 + 8192 + LADDR(c, hi))); } \
    acc[0][1] = __builtin_amdgcn_mfma_i32_16x16x64_i8(bF1, aF0, acc[0][1], 0, 0, 0); \
    acc[1][1] = __builtin_amdgcn_mfma_i32_16x16x64_i8(bF1, aF1, acc[1][1], 0, 0, 0); \
    acc[2][1] = __builtin_amdgcn_mfma_i32_16x16x64_i8(bF1, aF2, acc[2][1], 0, 0, 0); \
    acc[3][1] = __builtin_amdgcn_mfma_i32_16x16x64_i8(bF1, aF3, acc[3][1], 0, 0, 0); \
    { const int c = wc * 64 + 48 + lo;                                        \
      bF3 = __builtin_bit_cast(i32x4, *(const uint4*)(smem + (BUF) * 24576 + 8192 + LADDR(c, hi))); } \
    acc[0][2] = __builtin_amdgcn_mfma_i32_16x16x64_i8(bF2, aF0, acc[0][2], 0, 0, 0); \
    acc[1][2] = __builtin_amdgcn_mfma_i32_16x16x64_i8(bF2, aF1, acc[1][2], 0, 0, 0); \
    acc[2][2] = __builtin_amdgcn_mfma_i32_16x16x64_i8(bF2, aF2, acc[2][2], 0, 0, 0); \
    acc[3][2] = __builtin_amdgcn_mfma_i32_16x16x64_i8(bF2, aF3, acc[3][2], 0, 0, 0); \
    acc[0][3] = __builtin_amdgcn_mfma_i32_16x16x64_i8(bF3, aF0, acc[0][3], 0, 0, 0); \
    acc[1][3] = __builtin_amdgcn_mfma_i32_16x16x64_i8(bF3, aF1, acc[1][3], 0, 0, 0); \
    acc[2][3] = __builtin_amdgcn_mfma_i32_16x16x64_i8(bF3, aF2, acc[2][3], 0, 0, 0); \
    acc[3][3] = __builtin_amdgcn_mfma_i32_16x16x64_i8(bF3, aF3, acc[3][3], 0, 0, 0); \
    __builtin_amdgcn_s_setprio(0);                                            \
  }

#define WAITV3 { asm volatile("s_waitcnt vmcnt(3)" ::: "memory"); }
#define WAITV0 { asm volatile("s_waitcnt vmcnt(0)" ::: "memory"); }
#define BAR    { __builtin_amdgcn_s_barrier(); }

  STAGE(0, 0)
  STAGE(1, 1) WAITV3 BAR COMPUTE(0) BAR   // s=0
  STAGE(0, 2) WAITV3 BAR COMPUTE(1) BAR   // s=1
  STAGE(1, 3) WAITV3 BAR COMPUTE(0) BAR   // s=2
  WAITV0 BAR COMPUTE(1)                   // s=3

#undef STAGE
#undef LADDR
#undef COMPUTE
#undef WAITV3
#undef WAITV0
#undef BAR

  // epilogue: exact int keys; mls in the (retired) K-buffers.
  __syncthreads();
  int* mls = (int*)smem;                      // [128 rows][81] int = 41.5KB
  const int vb13 = 8191 - (col0 + wc * 64) - hi * 4;
#pragma unroll
  for (int aq = 0; aq < 4; ++aq) {
    int T0 = IMIN, T1 = IMIN, T2 = IMIN, T3 = IMIN, T4 = IMIN;
    const int arow = row0 + wr * 64 + aq * 16 + lo;
#pragma unroll
    for (int pq = 0; pq < 4; ++pq)
#pragma unroll
      for (int rr = 0; rr < 4; ++rr) {
        int key = (int)(((uint32_t)acc[aq][pq][rr]) << 13) + vb13 - (pq * 16 + rr);
        if (hasDiag) {
          if (col0 + wc * 64 + pq * 16 + hi * 4 + rr == arow) key = IMIN;
        }
        FINS5I(T0, T1, T2, T3, T4, key);
      }
    int* dst = mls + (wr * 64 + aq * 16 + lo) * 81 + (wc * 4 + hi) * 5;
    dst[0] = T0; dst[1] = T1; dst[2] = T2; dst[3] = T3; dst[4] = T4;
  }
  __syncthreads();

  // block-level merge: 2 threads/row x 40 keys, then shfl_xor(1) pair-merge
  if (tid < 256) {
    const int row = tid >> 1, half = tid & 1;
    const int* s2 = mls + row * 81 + half * 40;
    int M0 = IMIN, M1 = IMIN, M2 = IMIN, M3 = IMIN, M4 = IMIN;
#pragma unroll
    for (int k = 0; k < 40; ++k) FINS5I(M0, M1, M2, M3, M4, s2[k]);
    const int c0 = __shfl_xor(M0, 1), c1 = __shfl_xor(M1, 1),
              c2 = __shfl_xor(M2, 1), c3 = __shfl_xor(M3, 1),
              c4 = __shfl_xor(M4, 1);
    FINS5I(M0, M1, M2, M3, M4, c0);
    FINS5I(M0, M1, M2, M3, M4, c1);
    FINS5I(M0, M1, M2, M3, M4, c2);
    FINS5I(M0, M1, M2, M3, M4, c3);
    FINS5I(M0, M1, M2, M3, M4, c4);
    if (half == 0) {
      int* dst = part + ((size_t)(row0 + row) * NCG + cb) * 5;
      dst[0] = M0; dst[1] = M1; dst[2] = M2; dst[3] = M3; dst[4] = M4;
    }
  }
}

// ---------------- merge splits + RNG + exact fp32 loss (4 rows/block) ----------------
__global__ __launch_bounds__(256) void merge_loss_kernel(
    const float* __restrict__ x, const int* __restrict__ part,
    float* __restrict__ rowloss,
    uint32_t k1a, uint32_t k1b, uint32_t k2a, uint32_t k2b) {
  const int w = threadIdx.x >> 6, l = threadIdx.x & 63;
  const int i = blockIdx.x * 4 + w;
  __shared__ int cs[4][160];
  const int* src = part + (size_t)i * (NCG * 5);
  cs[w][l] = src[l];
  cs[w][64 + l] = src[64 + l];
  if (l < 32) cs[w][128 + l] = src[128 + l];
  __syncthreads();

  int T0 = IMIN, T1 = IMIN, T2 = IMIN, T3 = IMIN, T4 = IMIN;
  for (int rch = 0; rch < NCG; ++rch) {
    for (int q = 0; q < 5; ++q) {      // runs sorted desc -> early out (uniform)
      const int c = cs[w][rch * 5 + q];
      if (c <= T4) break;
      FINS5C(T0, T1, T2, T3, T4, c);
    }
  }

  // RNG: coin = uniform(k1) < 0.5 <=> MSB==0 ; randint(k2,0,5)
  const uint32_t cw = rng_word(tf2x32(k1a, k1b, 0u, (uint32_t)i));
  const bool coin = (cw >> 31) == 0u;
  const uint32_t hb = rng_word(tf2x32(k2a, k2b, 0u, (uint32_t)i));
  const uint32_t lb = rng_word(tf2x32(k2a, k2b, 0u, (uint32_t)(NB + i)));
  const int rr = (int)(((hb % 5u) + (lb % 5u)) % 5u);
  const int rank = coin ? 0 : rr;
  const int kch = (rank == 0) ? T0 : (rank == 1) ? T1 : (rank == 2) ? T2
                : (rank == 3) ? T3 : T4;
  const int neg = 8191 - (kch & 8191);

  // exact fp32 loss from raw x
  const float4 xa = *(const float4*)(x + (size_t)i * 512 + l * 4);
  const float4 xp = *(const float4*)(x + (size_t)i * 512 + 256 + l * 4);
  const float4 xn = *(const float4*)(x + (size_t)neg * 512 + 256 + l * 4);
  float sa = xa.x * xa.x + xa.y * xa.y + xa.z * xa.z + xa.w * xa.w;
  float sp = xp.x * xp.x + xp.y * xp.y + xp.z * xp.z + xp.w * xp.w;
  float sn = xn.x * xn.x + xn.y * xn.y + xn.z * xn.z + xn.w * xn.w;
#pragma unroll
  for (int off = 32; off; off >>= 1) {
    sa += __shfl_xor(sa, off); sp += __shfl_xor(sp, off); sn += __shfl_xor(sn, off);
  }
  const float na = fmaxf(sqrtf(sa), 1e-12f);
  const float np = fmaxf(sqrtf(sp), 1e-12f);
  const float nn = fmaxf(sqrtf(sn), 1e-12f);

  float pos = 0.f, ng = 0.f;
  {
    float av, pv, nv, dp, dn;
    av = xa.x / na; pv = xp.x / np; nv = xn.x / nn;
    dp = av - pv + EPSF; pos += dp * dp; dn = av - nv + EPSF; ng += dn * dn;
    av = xa.y / na; pv = xp.y / np; nv = xn.y / nn;
    dp = av - pv + EPSF; pos += dp * dp; dn = av - nv + EPSF; ng += dn * dn;
    av = xa.z / na; pv = xp.z / np; nv = xn.z / nn;
    dp = av - pv + EPSF; pos += dp * dp; dn = av - nv + EPSF; ng += dn * dn;
    av = xa.w / na; pv = xp.w / np; nv = xn.w / nn;
    dp = av - pv + EPSF; pos += dp * dp; dn = av - nv + EPSF; ng += dn * dn;
  }
#pragma unroll
  for (int off = 32; off; off >>= 1) {
    pos += __shfl_xor(pos, off); ng += __shfl_xor(ng, off);
  }
  if (l == 0) rowloss[i] = fmaxf(pos - ng, 0.0f);
}

// ---------------- deterministic mean ----------------
__global__ __launch_bounds__(256) void finalize_kernel(
    const float* __restrict__ rowloss, float* __restrict__ out) {
  __shared__ float s[256];
  const int t = threadIdx.x;
  float a = 0.f;
  for (int k = 0; k < NB / 256; ++k) a += rowloss[t + 256 * k];
  s[t] = a;
  __syncthreads();
  for (int h = 128; h; h >>= 1) {
    if (t < h) s[t] += s[t + h];
    __syncthreads();
  }
  if (t == 0) out[0] = s[0] / (float)NB;
}

extern "C" void kernel_launch(void* const* d_in, const int* in_sizes, int n_in,
                              void* d_out, int out_size, void* d_ws, size_t ws_size,
                              hipStream_t stream) {
  (void)in_sizes; (void)n_in; (void)out_size; (void)ws_size;
  const float* x = (const float*)d_in[0];
  float* out = (float*)d_out;
  char* ws = (char*)d_ws;

  char* aq8 = ws;                                                        // 2 MB
  char* pq8 = ws + (size_t)2 * 1024 * 1024;                              // 2 MB
  int* part = (int*)(ws + (size_t)4 * 1024 * 1024);                      // 5.24 MB
  float* rowloss = (float*)(ws + (size_t)4 * 1024 * 1024 +
                            (size_t)NB * NCG * 5 * sizeof(int));         // 32 KB

  // JAX: kr = key(1); k1, k2 = split(kr)  (threefry partitionable)
  U2 c0 = tf2x32(0u, 1u, 0u, 0u);
  U2 c1 = tf2x32(0u, 1u, 0u, 1u);
  const uint32_t k1a = c0.x, k1b = c0.y;
  const uint32_t k2a = c1.x, k2b = c1.y;

  prep_kernel<<<NB / 4, 256, 0, stream>>>(x, aq8, pq8);
  dist_topk_kernel<<<2048, 512, 0, stream>>>(aq8, pq8, part);
  merge_loss_kernel<<<NB / 4, 256, 0, stream>>>(x, part, rowloss, k1a, k1b, k2a, k2b);
  finalize_kernel<<<1, 256, 0, stream>>>(rowloss, out);
}

// Round 19
// 59.214 us; speedup vs baseline: 1.8405x; 1.0165x over previous
//
#include <hip/hip_runtime.h>
#include <hip/hip_bf16.h>
#include <stdint.h>

// B=8192 triplet loss with hard-negative mining.
// prep: normalize -> int8 (x127); loss recomputed exactly from fp32 x.
// dist_topk: TRIPLE-buffered counted-vmcnt i8 GEMM (128x256 tile, BK=64,
//            4 K-steps, ONE barrier/step — buffer written at step s was last
//            read at s-2, so the availability barrier also read-protects).
//            Paired-row swizzle (0 conflicts), fine interleave, setprio.
//            Mining: EXACT int keys (acc<<13)+(8191-ci) + v_med3_i32 insert,
//            diag branch hoisted (block-uniform, 64/2048 blocks).
// merge_loss: merge 32 sorted runs -> rowloss (no atomics/fences).
// finalize: deterministic mean (1 block).

#define NB 8192
#define NCG 32        // col-groups of 256
#define EPSF 1e-6f
#define IMIN (-2147483647 - 1)

typedef int i32x4 __attribute__((ext_vector_type(4)));

struct U2 { uint32_t x, y; };

__host__ __device__ __forceinline__ uint32_t rotl32(uint32_t v, int n) {
  return (v << n) | (v >> (32 - n));
}

__host__ __device__ __forceinline__ U2 tf2x32(uint32_t k0, uint32_t k1,
                                              uint32_t x0, uint32_t x1) {
  uint32_t k2 = k0 ^ k1 ^ 0x1BD11BDAu;
#define TF_R(r) { x0 += x1; x1 = rotl32(x1, r); x1 ^= x0; }
  x0 += k0; x1 += k1;
  TF_R(13) TF_R(15) TF_R(26) TF_R(6)
  x0 += k1; x1 += k2 + 1u;
  TF_R(17) TF_R(29) TF_R(16) TF_R(24)
  x0 += k2; x1 += k0 + 2u;
  TF_R(13) TF_R(15) TF_R(26) TF_R(6)
  x0 += k0; x1 += k1 + 3u;
  TF_R(17) TF_R(29) TF_R(16) TF_R(24)
  x0 += k1; x1 += k2 + 4u;
  TF_R(13) TF_R(15) TF_R(26) TF_R(6)
  x0 += k2; x1 += k0 + 5u;
#undef TF_R
  U2 r; r.x = x0; r.y = x1; return r;
}

__device__ __forceinline__ uint32_t rng_word(U2 r) { return r.x ^ r.y; }

// int top-5 insert into sorted-desc T0..T4 via med3 (valid since T sorted):
#define FINS5I(T0, T1, T2, T3, T4, C) {           \
    const int _c = (C), _t0 = T0, _t1 = T1, _t2 = T2, _t3 = T3, _t4 = T4; \
    T0 = _t0 > _c ? _t0 : _c;                     \
    asm("v_med3_i32 %0, %1, %2, %3" : "=v"(T1) : "v"(_c), "v"(_t0), "v"(_t1)); \
    asm("v_med3_i32 %0, %1, %2, %3" : "=v"(T2) : "v"(_c), "v"(_t1), "v"(_t2)); \
    asm("v_med3_i32 %0, %1, %2, %3" : "=v"(T3) : "v"(_c), "v"(_t2), "v"(_t3)); \
    asm("v_med3_i32 %0, %1, %2, %3" : "=v"(T4) : "v"(_c), "v"(_t3), "v"(_t4)); }

// plain C version (merge_loss early-out loop)
#define FINS5C(T0, T1, T2, T3, T4, C) {           \
    const int _t0 = T0, _t1 = T1, _t2 = T2, _t3 = T3, _t4 = T4, _c = C; \
    T0 = _t0 > _c ? _t0 : _c;                     \
    { const int m = _c < _t0 ? _c : _t0; T1 = _t1 > m ? _t1 : m; } \
    { const int m = _c < _t1 ? _c : _t1; T2 = _t2 > m ? _t2 : m; } \
    { const int m = _c < _t2 ? _c : _t2; T3 = _t3 > m ? _t3 : m; } \
    { const int m = _c < _t3 ? _c : _t3; T4 = _t4 > m ? _t4 : m; } }

__device__ __forceinline__ void gload16(const void* g, void* l) {
  __builtin_amdgcn_global_load_lds(
      (const __attribute__((address_space(1))) unsigned int*)g,
      (__attribute__((address_space(3))) unsigned int*)l, 16, 0, 0);
}

// ---------------- prep: normalize -> int8 (x127) ----------------
__global__ __launch_bounds__(256) void prep_kernel(
    const float* __restrict__ x,
    char* __restrict__ aq8, char* __restrict__ pq8) {
  const int w = threadIdx.x >> 6, l = threadIdx.x & 63;
  const int row = blockIdx.x * 4 + w;
  const float4* xr = (const float4*)(x + (size_t)row * 512);
  const float4 a4 = xr[l];
  const float4 p4 = xr[64 + l];
  float sa = a4.x * a4.x + a4.y * a4.y + a4.z * a4.z + a4.w * a4.w;
  float sp = p4.x * p4.x + p4.y * p4.y + p4.z * p4.z + p4.w * p4.w;
#pragma unroll
  for (int off = 32; off; off >>= 1) { sa += __shfl_xor(sa, off); sp += __shfl_xor(sp, off); }
  const float ia = 127.0f / fmaxf(sqrtf(sa), 1e-12f);
  const float ip_ = 127.0f / fmaxf(sqrtf(sp), 1e-12f);
  const int qa0 = (int)rintf(a4.x * ia), qa1 = (int)rintf(a4.y * ia);
  const int qa2 = (int)rintf(a4.z * ia), qa3 = (int)rintf(a4.w * ia);
  const int qp0 = (int)rintf(p4.x * ip_), qp1 = (int)rintf(p4.y * ip_);
  const int qp2 = (int)rintf(p4.z * ip_), qp3 = (int)rintf(p4.w * ip_);
  const uint32_t ua = (qa0 & 255) | ((qa1 & 255) << 8) |
                      ((qa2 & 255) << 16) | ((uint32_t)(qa3 & 255) << 24);
  const uint32_t up = (qp0 & 255) | ((qp1 & 255) << 8) |
                      ((qp2 & 255) << 16) | ((uint32_t)(qp3 & 255) << 24);
  *(uint32_t*)(aq8 + (size_t)row * 256 + l * 4) = ua;
  *(uint32_t*)(pq8 + (size_t)row * 256 + l * 4) = up;
}

// ---------------- dist + per-row top-5 (i8, triple-buffered) ----------------
// grid: 2048 blocks (64 rb x 32 cb, XCD supertile), 512 thr = 8 waves (2x4);
// wave (wr,wc) owns a-rows [rb*128+wr*64,+64) x p-cols [cb*256+wc*64,+64).
// LDS: 3 K-buffers x 24KB (A 128x64B 8KB + B 256x64B 16KB). Paired-row
// swizzle (0 conflicts). 4 K-steps of BK=64 (mfma_i32_16x16x64_i8), bufs
// cycle 0,1,2,0; ONE barrier/step (buffer rewritten 3 steps after last read).
// mfma(bF, aF): a-row (C col) = row0+wr*64+aq*16+lo;
// p-col (C row) = col0+wc*64+pq*16+hi*4+r.
__global__ __launch_bounds__(512, 2) void dist_topk_kernel(
    const char* __restrict__ aq8, const char* __restrict__ pq8,
    int* __restrict__ part) {
  __shared__ __align__(16) char smem[73728]; // buf0|buf1|buf2; reused as mls[128][81]

  const int tid = threadIdx.x;
  const int w = tid >> 6, l = tid & 63;
  const int lo = l & 15, hi = l >> 4;
  const int wr = w >> 2, wc = w & 3;

  const int b = blockIdx.x;
  const int xcd = b & 7, j = b >> 3;          // j: 0..255
  const int rb = (xcd >> 1) * 16 + (j >> 4);  // 0..63 (128 rows)
  const int cb = (xcd & 1) * 16 + (j & 15);   // 0..31 (256 cols)
  const int row0 = rb * 128, col0 = cb * 256;
  const bool hasDiag = (cb == (rb >> 1));

  i32x4 acc[4][4];
#pragma unroll
  for (int aq = 0; aq < 4; ++aq)
#pragma unroll
    for (int pq = 0; pq < 4; ++pq) { i32x4 z = {0, 0, 0, 0}; acc[aq][pq] = z; }

#define STAGE(BUF, KS)                                                        \
  {                                                                           \
    { const int off = tid * 16;                                               \
      const int R = off >> 7;                                                 \
      const int s = ((off >> 4) & 7) ^ (R & 7);                               \
      const int r = 2 * R + (s >> 2);                                         \
      const int kb = (s & 3) * 16;                                            \
      gload16(aq8 + (size_t)(row0 + r) * 256 + (KS) * 64 + kb,                \
              smem + (BUF) * 24576 + off); }                                  \
    _Pragma("unroll")                                                         \
    for (int jj = 0; jj < 2; ++jj) {                                          \
      const int off = jj * 8192 + tid * 16;                                   \
      const int R = off >> 7;                                                 \
      const int s = ((off >> 4) & 7) ^ (R & 7);                               \
      const int c = 2 * R + (s >> 2);                                         \
      const int kb = (s & 3) * 16;                                            \
      gload16(pq8 + (size_t)(col0 + c) * 256 + (KS) * 64 + kb,                \
              smem + (BUF) * 24576 + 8192 + off); }                           \
  }

#define LADDR(RR, T) (((RR) >> 1) * 128 + (((((RR) & 1) * 4 + (T)) ^ (((RR) >> 1) & 7)) * 16))

#define COMPUTE(BUF)                                                          \
  {                                                                           \
    i32x4 aF0, aF1, aF2, aF3, bF0, bF1, bF2, bF3;                             \
    { const int r = wr * 64 + 0 + lo;                                         \
      aF0 = __builtin_bit_cast(i32x4, *(const uint4*)(smem + (BUF) * 24576 + LADDR(r, hi))); } \
    { const int r = wr * 64 + 16 + lo;                                        \
      aF1 = __builtin_bit_cast(i32x4, *(const uint4*)(smem + (BUF) * 24576 + LADDR(r, hi))); } \
    { const int r = wr * 64 + 32 + lo;                                        \
      aF2 = __builtin_bit_cast(i32x4, *(const uint4*)(smem + (BUF) * 24576 + LADDR(r, hi))); } \
    { const int r = wr * 64 + 48 + lo;                                        \
      aF3 = __builtin_bit_cast(i32x4, *(const uint4*)(smem + (BUF) * 24576 + LADDR(r, hi))); } \
    { const int c = wc * 64 + 0 + lo;                                         \
      bF0 = __builtin_bit_cast(i32x4, *(const uint4*)(smem + (BUF) * 24576 + 8192 + LADDR(c, hi))); } \
    { const int c = wc * 64 + 16 + lo;                                        \
      bF1 = __builtin_bit_cast(i32x4, *(const uint4*)(smem + (BUF) * 24576 + 8192 + LADDR(c, hi))); } \
    __builtin_amdgcn_s_setprio(1);                                            \
    acc[0][0] = __builtin_amdgcn_mfma_i32_16x16x64_i8(bF0, aF0, acc[0][0], 0, 0, 0); \
    acc[1][0] = __builtin_amdgcn_mfma_i32_16x16x64_i8(bF0, aF1, acc[1][0], 0, 0, 0); \
    acc[2][0] = __builtin_amdgcn_mfma_i32_16x16x64_i8(bF0, aF2, acc[2][0], 0, 0, 0); \
    acc[3][0] = __builtin_amdgcn_mfma_i32_16x16x64_i8(bF0, aF3, acc[3][0], 0, 0, 0); \
    { const int c = wc * 64 + 32 + lo;                                        \
      bF2 = __builtin_bit_cast(i32x4, *(const uint4*)(smem + (BUF) * 24576 + 8192 + LADDR(c, hi))); } \
    acc[0][1] = __builtin_amdgcn_mfma_i32_16x16x64_i8(bF1, aF0, acc[0][1], 0, 0, 0); \
    acc[1][1] = __builtin_amdgcn_mfma_i32_16x16x64_i8(bF1, aF1, acc[1][1], 0, 0, 0); \
    acc[2][1] = __builtin_amdgcn_mfma_i32_16x16x64_i8(bF1, aF2, acc[2][1], 0, 0, 0); \
    acc[3][1] = __builtin_amdgcn_mfma_i32_16x16x64_i8(bF1, aF3, acc[3][1], 0, 0, 0); \
    { const int c = wc * 64 + 48 + lo;                                        \
      bF3 = __builtin_bit_cast(i32x4, *(const uint4*)(smem + (BUF) * 24576 + 8192 + LADDR(c, hi))); } \
    acc[0][2] = __builtin_amdgcn_mfma_i32_16x16x64_i8(bF2, aF0, acc[0][2], 0, 0, 0); \
    acc[1][2] = __builtin_amdgcn_mfma_i32_16x16x64_i8(bF2, aF1, acc[1][2], 0, 0, 0); \
    acc[2][2] = __builtin_amdgcn_mfma_i32_16x16x64_i8(bF2, aF2, acc[2][2], 0, 0, 0); \
    acc[3][2] = __builtin_amdgcn_mfma_i32_16x16x64_i8(bF2, aF3, acc[3][2], 0, 0, 0); \
    acc[0][3] = __builtin_amdgcn_mfma_i32_16x16x64_i8(bF3, aF0, acc[0][3], 0, 0, 0); \
    acc[1][3] = __builtin_amdgcn_mfma_i32_16x16x64_i8(bF3, aF1, acc[1][3], 0, 0, 0); \
    acc[2][3] = __builtin_amdgcn_mfma_i32_16x16x64_i8(bF3, aF2, acc[2][3], 0, 0, 0); \
    acc[3][3] = __builtin_amdgcn_mfma_i32_16x16x64_i8(bF3, aF3, acc[3][3], 0, 0, 0); \
    __builtin_amdgcn_s_setprio(0);                                            \
  }

#define WAITV3 { asm volatile("s_waitcnt vmcnt(3)" ::: "memory"); }
#define WAITV0 { asm volatile("s_waitcnt vmcnt(0)" ::: "memory"); }
#define BAR    { __builtin_amdgcn_s_barrier(); }

  // triple-buffered, 1 barrier/step: WAITV(avail) BAR covers both data
  // availability and read-retirement (writes go to a buffer last read 3
  // steps ago; arrival at BAR implies the prior COMPUTE's reads retired).
  STAGE(0, 0)
  STAGE(1, 1)
  WAITV3 BAR STAGE(2, 2) COMPUTE(0)   // s=0: wait stage0, prefetch k2
  WAITV3 BAR STAGE(0, 3) COMPUTE(1)   // s=1: wait stage1, prefetch k3 -> buf0
  WAITV3 BAR COMPUTE(2)               // s=2: wait stage2
  WAITV0 BAR COMPUTE(0)               // s=3: wait stage3 (in buf0)

#undef STAGE
#undef LADDR
#undef COMPUTE
#undef WAITV3
#undef WAITV0
#undef BAR

  // epilogue: exact int keys; mls in the (retired) K-buffers.
  __syncthreads();
  int* mls = (int*)smem;                      // [128 rows][81] int = 41.5KB
  const int vb13 = 8191 - (col0 + wc * 64) - hi * 4;

#define MINE_LOOP(DIAG)                                                       \
  _Pragma("unroll")                                                           \
  for (int aq = 0; aq < 4; ++aq) {                                            \
    int T0 = IMIN, T1 = IMIN, T2 = IMIN, T3 = IMIN, T4 = IMIN;                \
    const int arow = row0 + wr * 64 + aq * 16 + lo;                           \
    _Pragma("unroll")                                                         \
    for (int pq = 0; pq < 4; ++pq)                                            \
      _Pragma("unroll")                                                       \
      for (int rr = 0; rr < 4; ++rr) {                                        \
        int key = (int)(((uint32_t)acc[aq][pq][rr]) << 13) + vb13 - (pq * 16 + rr); \
        if (DIAG) {                                                           \
          if (col0 + wc * 64 + pq * 16 + hi * 4 + rr == arow) key = IMIN;     \
        }                                                                     \
        FINS5I(T0, T1, T2, T3, T4, key);                                      \
      }                                                                       \
    int* dst = mls + (wr * 64 + aq * 16 + lo) * 81 + (wc * 4 + hi) * 5;       \
    dst[0] = T0; dst[1] = T1; dst[2] = T2; dst[3] = T3; dst[4] = T4;          \
  }

  if (hasDiag) { MINE_LOOP(true) } else { MINE_LOOP(false) }
#undef MINE_LOOP
  __syncthreads();

  // block-level merge: 2 threads/row x 40 keys, then shfl_xor(1) pair-merge
  if (tid < 256) {
    const int row = tid >> 1, half = tid & 1;
    const int* s2 = mls + row * 81 + half * 40;
    int M0 = IMIN, M1 = IMIN, M2 = IMIN, M3 = IMIN, M4 = IMIN;
#pragma unroll
    for (int k = 0; k < 40; ++k) FINS5I(M0, M1, M2, M3, M4, s2[k]);
    const int c0 = __shfl_xor(M0, 1), c1 = __shfl_xor(M1, 1),
              c2 = __shfl_xor(M2, 1), c3 = __shfl_xor(M3, 1),
              c4 = __shfl_xor(M4, 1);
    FINS5I(M0, M1, M2, M3, M4, c0);
    FINS5I(M0, M1, M2, M3, M4, c1);
    FINS5I(M0, M1, M2, M3, M4, c2);
    FINS5I(M0, M1, M2, M3, M4, c3);
    FINS5I(M0, M1, M2, M3, M4, c4);
    if (half == 0) {
      int* dst = part + ((size_t)(row0 + row) * NCG + cb) * 5;
      dst[0] = M0; dst[1] = M1; dst[2] = M2; dst[3] = M3; dst[4] = M4;
    }
  }
}

// ---------------- merge splits + RNG + exact fp32 loss (4 rows/block) ----------------
__global__ __launch_bounds__(256) void merge_loss_kernel(
    const float* __restrict__ x, const int* __restrict__ part,
    float* __restrict__ rowloss,
    uint32_t k1a, uint32_t k1b, uint32_t k2a, uint32_t k2b) {
  const int w = threadIdx.x >> 6, l = threadIdx.x & 63;
  const int i = blockIdx.x * 4 + w;
  __shared__ int cs[4][160];
  const int* src = part + (size_t)i * (NCG * 5);
  cs[w][l] = src[l];
  cs[w][64 + l] = src[64 + l];
  if (l < 32) cs[w][128 + l] = src[128 + l];
  __syncthreads();

  int T0 = IMIN, T1 = IMIN, T2 = IMIN, T3 = IMIN, T4 = IMIN;
  for (int rch = 0; rch < NCG; ++rch) {
    for (int q = 0; q < 5; ++q) {      // runs sorted desc -> early out (uniform)
      const int c = cs[w][rch * 5 + q];
      if (c <= T4) break;
      FINS5C(T0, T1, T2, T3, T4, c);
    }
  }

  // RNG: coin = uniform(k1) < 0.5 <=> MSB==0 ; randint(k2,0,5)
  const uint32_t cw = rng_word(tf2x32(k1a, k1b, 0u, (uint32_t)i));
  const bool coin = (cw >> 31) == 0u;
  const uint32_t hb = rng_word(tf2x32(k2a, k2b, 0u, (uint32_t)i));
  const uint32_t lb = rng_word(tf2x32(k2a, k2b, 0u, (uint32_t)(NB + i)));
  const int rr = (int)(((hb % 5u) + (lb % 5u)) % 5u);
  const int rank = coin ? 0 : rr;
  const int kch = (rank == 0) ? T0 : (rank == 1) ? T1 : (rank == 2) ? T2
                : (rank == 3) ? T3 : T4;
  const int neg = 8191 - (kch & 8191);

  // exact fp32 loss from raw x
  const float4 xa = *(const float4*)(x + (size_t)i * 512 + l * 4);
  const float4 xp = *(const float4*)(x + (size_t)i * 512 + 256 + l * 4);
  const float4 xn = *(const float4*)(x + (size_t)neg * 512 + 256 + l * 4);
  float sa = xa.x * xa.x + xa.y * xa.y + xa.z * xa.z + xa.w * xa.w;
  float sp = xp.x * xp.x + xp.y * xp.y + xp.z * xp.z + xp.w * xp.w;
  float sn = xn.x * xn.x + xn.y * xn.y + xn.z * xn.z + xn.w * xn.w;
#pragma unroll
  for (int off = 32; off; off >>= 1) {
    sa += __shfl_xor(sa, off); sp += __shfl_xor(sp, off); sn += __shfl_xor(sn, off);
  }
  const float na = fmaxf(sqrtf(sa), 1e-12f);
  const float np = fmaxf(sqrtf(sp), 1e-12f);
  const float nn = fmaxf(sqrtf(sn), 1e-12f);

  float pos = 0.f, ng = 0.f;
  {
    float av, pv, nv, dp, dn;
    av = xa.x / na; pv = xp.x / np; nv = xn.x / nn;
    dp = av - pv + EPSF; pos += dp * dp; dn = av - nv + EPSF; ng += dn * dn;
    av = xa.y / na; pv = xp.y / np; nv = xn.y / nn;
    dp = av - pv + EPSF; pos += dp * dp; dn = av - nv + EPSF; ng += dn * dn;
    av = xa.z / na; pv = xp.z / np; nv = xn.z / nn;
    dp = av - pv + EPSF; pos += dp * dp; dn = av - nv + EPSF; ng += dn * dn;
    av = xa.w / na; pv = xp.w / np; nv = xn.w / nn;
    dp = av - pv + EPSF; pos += dp * dp; dn = av - nv + EPSF; ng += dn * dn;
  }
#pragma unroll
  for (int off = 32; off; off >>= 1) {
    pos += __shfl_xor(pos, off); ng += __shfl_xor(ng, off);
  }
  if (l == 0) rowloss[i] = fmaxf(pos - ng, 0.0f);
}

// ---------------- deterministic mean ----------------
__global__ __launch_bounds__(256) void finalize_kernel(
    const float* __restrict__ rowloss, float* __restrict__ out) {
  __shared__ float s[256];
  const int t = threadIdx.x;
  float a = 0.f;
  for (int k = 0; k < NB / 256; ++k) a += rowloss[t + 256 * k];
  s[t] = a;
  __syncthreads();
  for (int h = 128; h; h >>= 1) {
    if (t < h) s[t] += s[t + h];
    __syncthreads();
  }
  if (t == 0) out[0] = s[0] / (float)NB;
}

extern "C" void kernel_launch(void* const* d_in, const int* in_sizes, int n_in,
                              void* d_out, int out_size, void* d_ws, size_t ws_size,
                              hipStream_t stream) {
  (void)in_sizes; (void)n_in; (void)out_size; (void)ws_size;
  const float* x = (const float*)d_in[0];
  float* out = (float*)d_out;
  char* ws = (char*)d_ws;

  char* aq8 = ws;                                                        // 2 MB
  char* pq8 = ws + (size_t)2 * 1024 * 1024;                              // 2 MB
  int* part = (int*)(ws + (size_t)4 * 1024 * 1024);                      // 5.24 MB
  float* rowloss = (float*)(ws + (size_t)4 * 1024 * 1024 +
                            (size_t)NB * NCG * 5 * sizeof(int));         // 32 KB

  // JAX: kr = key(1); k1, k2 = split(kr)  (threefry partitionable)
  U2 c0 = tf2x32(0u, 1u, 0u, 0u);
  U2 c1 = tf2x32(0u, 1u, 0u, 1u);
  const uint32_t k1a = c0.x, k1b = c0.y;
  const uint32_t k2a = c1.x, k2b = c1.y;

  prep_kernel<<<NB / 4, 256, 0, stream>>>(x, aq8, pq8);
  dist_topk_kernel<<<2048, 512, 0, stream>>>(aq8, pq8, part);
  merge_loss_kernel<<<NB / 4, 256, 0, stream>>>(x, part, rowloss, k1a, k1b, k2a, k2b);
  finalize_kernel<<<1, 256, 0, stream>>>(rowloss, out);
}